// Round 7
// baseline (269.509 us; speedup 1.0000x reference)
//
#include <hip/hip_runtime.h>
#include <hip/hip_bf16.h>
#include <math.h>

#define KN 64
#define HO 124
#define KP 104
#define NOUT (128LL * 124 * 124 * 64)  // 125,960,192
#define NG 31                          // 124/4 ho-groups per image
#define NCONV (128 * NG)               // 3968 conv blocks
#define NSIG 1984                      // sigma blocks (grid-stride)

// ws layout: ssn 7,872,512 B | w_bf 13,312 B | sp 256 B
#define WS_SSN_OFF 0ULL
#define WS_WBF_OFF 7872512ULL
#define WS_SP_OFF 7885824ULL

typedef short bfrag8 __attribute__((ext_vector_type(8)));  // 8 bf16
typedef float ffrag4 __attribute__((ext_vector_type(4)));  // 4 f32

// round-to-nearest-even f32 -> bf16 bits (finite inputs)
__device__ __forceinline__ unsigned short f2bf(float f) {
    union { float f; unsigned u; } x;
    x.f = f;
    unsigned r = x.u + 0x7fffu + ((x.u >> 16) & 1u);
    return (unsigned short)(r >> 16);
}
__device__ __forceinline__ unsigned pack2(float a, float b) {
    return (unsigned)f2bf(a) | ((unsigned)f2bf(b) << 16);
}

// XOR-swizzled byte offset into s_im: [row][wo][16 bf16] = 32 B per (row,wo).
__device__ __forceinline__ int im_off(int row, int wo, int half) {
    return (((row * 128 + wo) * 32) + half * 16) ^ (((wo >> 2) & 7) << 4);
}

// -------- one-time prep: weight transpose->bf16 + softplus + KL scalar -----
__global__ void prep_kernel(const float* __restrict__ w_mu,
                            const float* __restrict__ w_sigma,
                            unsigned short* __restrict__ w_bf,
                            float* __restrict__ sp_out,
                            float* __restrict__ out_kl) {
    const int tid = threadIdx.x;       // 256
    const int n = tid >> 2;            // 64 rows, 4 threads each
    const int kbase = (tid & 3) * 26;  // 4*26 = 104
#pragma unroll
    for (int kk = 0; kk < 26; ++kk) {
        const int k = kbase + kk;
        float v = 0.f;
        if (k < 80) {
            const int r = k >> 4, t = k & 15;
            if (t < 15) v = w_mu[(r * 15 + t) * KN + n];
        }
        w_bf[n * KP + k] = f2bf(v);
    }
    if (tid < KN) sp_out[tid] = log1pf(expf(w_sigma[tid]));

    // KL (first wave only)
    if (tid < 64) {
        float s = 0.f;
#pragma unroll
        for (int i = 0; i < 75; ++i) {
            float m = w_mu[i * KN + tid];
            s = fmaf(m, m, s);
        }
        float lv = w_sigma[tid];
        float sp = log1pf(expf(lv));
        float val = 1.0f + lv - sp - s * (1.0f / 75.0f);
#pragma unroll
        for (int off = 32; off > 0; off >>= 1) val += __shfl_down(val, off);
        if (tid == 0) {
            float kl = -(val / 64.0f);
            if (isnan(kl) || isinf(kl)) kl = 1e-5f;
            out_kl[0] = kl;
        }
    }
}

// ---------------- ssn prepass: patch sum-of-squares / 75 -------------------
__global__ void ssn_kernel(const float* __restrict__ mu_in,
                           float* __restrict__ ssn_ws) {
    __shared__ __align__(16) float s_cs[8 * 128];
    const int bid = blockIdx.x;
    const int b = bid / NG;
    const int ho0 = (bid % NG) * 4;
    const int tid = threadIdx.x;

    {
        const int r = tid >> 5;          // 0..7
        const int c4 = (tid & 31) << 2;  // 0..124
        const float* p = mu_in + ((size_t)(b * 128 + ho0 + r) * 384 + c4 * 3);
        float4 f0 = reinterpret_cast<const float4*>(p)[0];
        float4 f1 = reinterpret_cast<const float4*>(p)[1];
        float4 f2 = reinterpret_cast<const float4*>(p)[2];
        float4 cs;
        cs.x = f0.x * f0.x + f0.y * f0.y + f0.z * f0.z;
        cs.y = f0.w * f0.w + f1.x * f1.x + f1.y * f1.y;
        cs.z = f1.z * f1.z + f1.w * f1.w + f2.x * f2.x;
        cs.w = f2.y * f2.y + f2.z * f2.z + f2.w * f2.w;
        *reinterpret_cast<float4*>(&s_cs[r * 128 + c4]) = cs;
    }
    __syncthreads();

#pragma unroll
    for (int it = 0; it < 2; ++it) {
        const int idx = tid + it * 256;
        const int hl = idx >> 7, wo = idx & 127;
        if (wo < HO) {
            float s = 0.f;
#pragma unroll
            for (int r = 0; r < 5; ++r) {
                const float* cr = &s_cs[(hl + r) * 128 + wo];
                s += cr[0] + cr[1] + cr[2] + cr[3] + cr[4];
            }
            ssn_ws[((size_t)(b * HO) + ho0 + hl) * HO + wo] = s * (1.0f / 75.0f);
        }
    }
}

// im2col fill: wave-uniform alignment class. OFF = (3*wo) mod 4, constexpr.
template <int OFF>
__device__ __forceinline__ void im_fill(const float* __restrict__ mu_in,
                                        unsigned short* s_im, int b, int ho0,
                                        int lane, int wo) {
#pragma unroll
    for (int j = 0; j < 4; ++j) {
        const int row = ((lane >> 5) << 2) + j;  // 0..7
        uint4* dst0 =
            reinterpret_cast<uint4*>((char*)s_im + im_off(row, wo, 0));
        uint4* dst1 =
            reinterpret_cast<uint4*>((char*)s_im + im_off(row, wo, 1));
        if (wo >= 124) {
            *dst0 = make_uint4(0u, 0u, 0u, 0u);
            *dst1 = make_uint4(0u, 0u, 0u, 0u);
            continue;
        }
        const float* p =
            mu_in + ((size_t)(b * 128 + ho0 + row) * 384 + wo * 3 - OFF);
        float w[20];
        float4 f;
        f = reinterpret_cast<const float4*>(p)[0];
        w[0] = f.x; w[1] = f.y; w[2] = f.z; w[3] = f.w;
        f = reinterpret_cast<const float4*>(p)[1];
        w[4] = f.x; w[5] = f.y; w[6] = f.z; w[7] = f.w;
        f = reinterpret_cast<const float4*>(p)[2];
        w[8] = f.x; w[9] = f.y; w[10] = f.z; w[11] = f.w;
        f = reinterpret_cast<const float4*>(p)[3];
        w[12] = f.x; w[13] = f.y; w[14] = f.z; w[15] = f.w;
        if (OFF >= 2) {
            f = reinterpret_cast<const float4*>(p)[4];
            w[16] = f.x; w[17] = f.y; w[18] = f.z; w[19] = f.w;
        } else {
            w[16] = 0.f; w[17] = 0.f; w[18] = 0.f; w[19] = 0.f;
        }
        unsigned u0 = pack2(w[OFF + 0], w[OFF + 1]);
        unsigned u1 = pack2(w[OFF + 2], w[OFF + 3]);
        unsigned u2 = pack2(w[OFF + 4], w[OFF + 5]);
        unsigned u3 = pack2(w[OFF + 6], w[OFF + 7]);
        unsigned u4 = pack2(w[OFF + 8], w[OFF + 9]);
        unsigned u5 = pack2(w[OFF + 10], w[OFF + 11]);
        unsigned u6 = pack2(w[OFF + 12], w[OFF + 13]);
        unsigned u7 = pack2(w[OFF + 14], 0.0f);  // t=15: weight is zero
        *dst0 = make_uint4(u0, u1, u2, u3);
        *dst1 = make_uint4(u4, u5, u6, u7);
    }
}

// ---------------- fused mega-kernel: conv blocks + sigma-writer blocks -----
// blockIdx % 3 == 2 -> sigma streaming block; else conv block. Sigma blocks
// (no LDS phase, pure stores) keep HBM busy while conv blocks stage/MFMA.
__global__ __launch_bounds__(256, 4) void fused_kernel(
    const float* __restrict__ mu_in,
    const unsigned short* __restrict__ w_bf,
    const float* __restrict__ ssn_ws, const float* __restrict__ sp_in,
    float* __restrict__ mu_out, float4* __restrict__ sig_out) {

    __shared__ __align__(16) unsigned short s_im[8 * 128 * 16];  // 32 KB

    const int bid = blockIdx.x;
    const int tid = threadIdx.x;

    if (bid % 3 == 2) {
        // ---- sigma path: 62 grid-strided 16B chunk stores per thread ----
        const long long NT = (long long)NSIG * 256;
        long long g = (long long)(bid / 3) * 256 + tid;
        const float4 sp4 = reinterpret_cast<const float4*>(sp_in)[tid & 15];
#pragma unroll 2
        for (int it = 0; it < 62; ++it, g += NT) {
            const float s = ssn_ws[g >> 4];
            sig_out[g] =
                make_float4(sp4.x * s, sp4.y * s, sp4.z * s, sp4.w * s);
        }
        return;
    }

    // ---- conv path ----
    const int cid = (bid / 3) * 2 + (bid % 3);  // 0 .. 3967
    const int b = cid / NG;
    const int ho0 = (cid % NG) * 4;
    const int lane = tid & 63;
    const int wid = tid >> 6;
    const int llo = lane & 15;
    const int lhi = lane >> 4;

    // weights -> regs (L2-hot)
    bfrag8 afr[4][3];
#pragma unroll
    for (int mt = 0; mt < 4; ++mt)
#pragma unroll
        for (int ks = 0; ks < 3; ++ks)
            afr[mt][ks] = *reinterpret_cast<const bfrag8*>(
                &w_bf[(mt * 16 + llo) * KP + ks * 32 + lhi * 8]);

    // im2col (each wave owns one wo mod-4 class)
    {
        const int wo = wid + ((lane & 31) << 2);
        switch (wid) {  // OFF = (3*class) mod 4
            case 0: im_fill<0>(mu_in, s_im, b, ho0, lane, wo); break;
            case 1: im_fill<3>(mu_in, s_im, b, ho0, lane, wo); break;
            case 2: im_fill<2>(mu_in, s_im, b, ho0, lane, wo); break;
            default: im_fill<1>(mu_in, s_im, b, ho0, lane, wo); break;
        }
    }
    __syncthreads();

#pragma unroll
    for (int hl = 0; hl < 4; ++hl) {
        ffrag4 acc[2][4];
#pragma unroll
        for (int nt = 0; nt < 2; ++nt)
#pragma unroll
            for (int mt = 0; mt < 4; ++mt)
                acc[nt][mt] = (ffrag4){0.f, 0.f, 0.f, 0.f};

#pragma unroll
        for (int nt = 0; nt < 2; ++nt) {
            const int wo = (wid * 2 + nt) * 16 + llo;
#pragma unroll
            for (int ks = 0; ks < 3; ++ks) {
                const int k0 = ks * 32 + lhi * 8;
                const int r = k0 >> 4;  // 0..5 (5 => k>=80: zero operand)
                bfrag8 bfr = (bfrag8){0, 0, 0, 0, 0, 0, 0, 0};
                if (r < 5) {
                    bfr = *reinterpret_cast<const bfrag8*>(
                        (char*)s_im + im_off(hl + r, wo, (k0 & 15) >> 3));
                }
#pragma unroll
                for (int mt = 0; mt < 4; ++mt)
                    acc[nt][mt] = __builtin_amdgcn_mfma_f32_16x16x32_bf16(
                        afr[mt][ks], bfr, acc[nt][mt], 0, 0, 0);
            }
        }

        const size_t orow = (size_t)(b * HO + ho0 + hl) * (size_t)(HO * KN);
#pragma unroll
        for (int nt = 0; nt < 2; ++nt) {
            const int wo = (wid * 2 + nt) * 16 + llo;
            if (wo < HO) {
                const size_t obase = orow + (size_t)wo * KN;
#pragma unroll
                for (int mt = 0; mt < 4; ++mt) {
                    const int knb = mt * 16 + lhi * 4;
                    *reinterpret_cast<float4*>(&mu_out[obase + knb]) =
                        make_float4(acc[nt][mt][0], acc[nt][mt][1],
                                    acc[nt][mt][2], acc[nt][mt][3]);
                }
            }
        }
    }
}

extern "C" void kernel_launch(void* const* d_in, const int* in_sizes, int n_in,
                              void* d_out, int out_size, void* d_ws,
                              size_t ws_size, hipStream_t stream) {
    const float* mu_in = (const float*)d_in[0];
    const float* w_mu = (const float*)d_in[1];
    const float* w_sigma = (const float*)d_in[2];
    float* out = (float*)d_out;

    float* mu_out = out;             // N floats
    float* sig_out = out + NOUT;     // N floats
    float* kl_out = out + 2 * NOUT;  // 1 float

    char* ws = (char*)d_ws;
    float* ssn_ws = (float*)(ws + WS_SSN_OFF);
    unsigned short* w_bf = (unsigned short*)(ws + WS_WBF_OFF);
    float* sp_ws = (float*)(ws + WS_SP_OFF);

    prep_kernel<<<1, 256, 0, stream>>>(w_mu, w_sigma, w_bf, sp_ws, kl_out);
    ssn_kernel<<<128 * NG, 256, 0, stream>>>(mu_in, ssn_ws);
    fused_kernel<<<NCONV / 2 * 3, 256, 0, stream>>>(
        mu_in, w_bf, ssn_ws, sp_ws, mu_out, (float4*)sig_out);
}

// Round 8
// 263.254 us; speedup vs baseline: 1.0238x; 1.0238x over previous
//
#include <hip/hip_runtime.h>
#include <hip/hip_bf16.h>
#include <math.h>

#define KN 64
#define HO 124
#define KP 104
#define NOUT (128LL * 124 * 124 * 64)  // 125,960,192
#define NG 31                          // ho-groups (of 4) per image
#define NCONV (128 * NG)               // 3968 groups total
#define GPB 4                          // groups per conv block (pipelined)
#define NBLK (NCONV / GPB)             // 992 conv blocks

// ws layout: ssn 7,872,512 B | w_bf 13,312 B | sp 256 B
#define WS_SSN_OFF 0ULL
#define WS_WBF_OFF 7872512ULL
#define WS_SP_OFF 7885824ULL

typedef short bfrag8 __attribute__((ext_vector_type(8)));  // 8 bf16
typedef float ffrag4 __attribute__((ext_vector_type(4)));  // 4 f32

__device__ __forceinline__ unsigned short f2bf(float f) {
    union { float f; unsigned u; } x;
    x.f = f;
    unsigned r = x.u + 0x7fffu + ((x.u >> 16) & 1u);
    return (unsigned short)(r >> 16);
}
__device__ __forceinline__ unsigned pack2(float a, float b) {
    return (unsigned)f2bf(a) | ((unsigned)f2bf(b) << 16);
}

// XOR-swizzled byte offset into s_im: [row][wo][16 bf16] = 32 B per (row,wo).
__device__ __forceinline__ int im_off(int row, int wo, int half) {
    return (((row * 128 + wo) * 32) + half * 16) ^ (((wo >> 2) & 7) << 4);
}

// raw barrier WITHOUT vmcnt drain (mu stores are never read by anyone;
// LDS visibility is handled by an explicit lgkmcnt(0) before the barrier)
__device__ __forceinline__ void block_sync_nodrain() {
    __builtin_amdgcn_sched_barrier(0);
    __builtin_amdgcn_s_barrier();
    __builtin_amdgcn_sched_barrier(0);
}
__device__ __forceinline__ void lds_flush() {
    asm volatile("s_waitcnt lgkmcnt(0)" ::: "memory");
}

// -------- one-time prep: weight transpose->bf16 + softplus + KL scalar -----
__global__ void prep_kernel(const float* __restrict__ w_mu,
                            const float* __restrict__ w_sigma,
                            unsigned short* __restrict__ w_bf,
                            float* __restrict__ sp_out,
                            float* __restrict__ out_kl) {
    const int tid = threadIdx.x;       // 256
    const int n = tid >> 2;            // 64 rows, 4 threads each
    const int kbase = (tid & 3) * 26;  // 4*26 = 104
#pragma unroll
    for (int kk = 0; kk < 26; ++kk) {
        const int k = kbase + kk;
        float v = 0.f;
        if (k < 80) {
            const int r = k >> 4, t = k & 15;
            if (t < 15) v = w_mu[(r * 15 + t) * KN + n];
        }
        w_bf[n * KP + k] = f2bf(v);
    }
    if (tid < KN) sp_out[tid] = log1pf(expf(w_sigma[tid]));

    if (tid < 64) {
        float s = 0.f;
#pragma unroll
        for (int i = 0; i < 75; ++i) {
            float m = w_mu[i * KN + tid];
            s = fmaf(m, m, s);
        }
        float lv = w_sigma[tid];
        float sp = log1pf(expf(lv));
        float val = 1.0f + lv - sp - s * (1.0f / 75.0f);
#pragma unroll
        for (int off = 32; off > 0; off >>= 1) val += __shfl_down(val, off);
        if (tid == 0) {
            float kl = -(val / 64.0f);
            if (isnan(kl) || isinf(kl)) kl = 1e-5f;
            out_kl[0] = kl;
        }
    }
}

// ---------------- ssn prepass: patch sum-of-squares / 75 -------------------
__global__ void ssn_kernel(const float* __restrict__ mu_in,
                           float* __restrict__ ssn_ws) {
    __shared__ __align__(16) float s_cs[8 * 128];
    const int bid = blockIdx.x;
    const int b = bid / NG;
    const int ho0 = (bid % NG) * 4;
    const int tid = threadIdx.x;

    {
        const int r = tid >> 5;          // 0..7
        const int c4 = (tid & 31) << 2;  // 0..124
        const float* p = mu_in + ((size_t)(b * 128 + ho0 + r) * 384 + c4 * 3);
        float4 f0 = reinterpret_cast<const float4*>(p)[0];
        float4 f1 = reinterpret_cast<const float4*>(p)[1];
        float4 f2 = reinterpret_cast<const float4*>(p)[2];
        float4 cs;
        cs.x = f0.x * f0.x + f0.y * f0.y + f0.z * f0.z;
        cs.y = f0.w * f0.w + f1.x * f1.x + f1.y * f1.y;
        cs.z = f1.z * f1.z + f1.w * f1.w + f2.x * f2.x;
        cs.w = f2.y * f2.y + f2.z * f2.z + f2.w * f2.w;
        *reinterpret_cast<float4*>(&s_cs[r * 128 + c4]) = cs;
    }
    __syncthreads();

#pragma unroll
    for (int it = 0; it < 2; ++it) {
        const int idx = tid + it * 256;
        const int hl = idx >> 7, wo = idx & 127;
        if (wo < HO) {
            float s = 0.f;
#pragma unroll
            for (int r = 0; r < 5; ++r) {
                const float* cr = &s_cs[(hl + r) * 128 + wo];
                s += cr[0] + cr[1] + cr[2] + cr[3] + cr[4];
            }
            ssn_ws[((size_t)(b * HO) + ho0 + hl) * HO + wo] = s * (1.0f / 75.0f);
        }
    }
}

// ---------------- sigma streaming kernel (fill-like) -----------------------
__global__ __launch_bounds__(256) void sigma_kernel(
    const float* __restrict__ ssn_ws, const float* __restrict__ sp_in,
    float4* __restrict__ sig_out) {
    const long long TOT = 128LL * 124 * 124 * 16;  // 31,490,048 chunks
    const long long NT = (long long)gridDim.x * 256;
    const long long g0 = (long long)blockIdx.x * 256 + threadIdx.x;
    const float4 sp4 = reinterpret_cast<const float4*>(sp_in)[g0 & 15];

    long long g = g0;
    for (; g + 3 * NT < TOT; g += 4 * NT) {
        const float s0 = ssn_ws[g >> 4];
        const float s1 = ssn_ws[(g + NT) >> 4];
        const float s2 = ssn_ws[(g + 2 * NT) >> 4];
        const float s3 = ssn_ws[(g + 3 * NT) >> 4];
        sig_out[g] = make_float4(sp4.x * s0, sp4.y * s0, sp4.z * s0, sp4.w * s0);
        sig_out[g + NT] =
            make_float4(sp4.x * s1, sp4.y * s1, sp4.z * s1, sp4.w * s1);
        sig_out[g + 2 * NT] =
            make_float4(sp4.x * s2, sp4.y * s2, sp4.z * s2, sp4.w * s2);
        sig_out[g + 3 * NT] =
            make_float4(sp4.x * s3, sp4.y * s3, sp4.z * s3, sp4.w * s3);
    }
    for (; g < TOT; g += NT) {
        const float s = ssn_ws[g >> 4];
        sig_out[g] = make_float4(sp4.x * s, sp4.y * s, sp4.z * s, sp4.w * s);
    }
}

// ---------------- conv staging helpers (load / pack split) -----------------
// One (row, wo) pair per call: 4-5 aligned float4 loads (proven in-bounds for
// wo<124: max float index read is 384 exclusive), pack 15 values + zero t=15.
template <int OFF>
__device__ __forceinline__ void pair_load(const float* __restrict__ mu_in,
                                          int b, int ho0, int row, int wo,
                                          float4 f[5]) {
    if (wo >= 124) return;  // pack writes zeros; f never read
    const float4* p = reinterpret_cast<const float4*>(
        mu_in + ((size_t)(b * 128 + ho0 + row) * 384 + wo * 3 - OFF));
    f[0] = p[0];
    f[1] = p[1];
    f[2] = p[2];
    f[3] = p[3];
    if constexpr (OFF >= 2) f[4] = p[4];
}

template <int OFF>
__device__ __forceinline__ void pair_pack(const float4 f[5], int wo, uint4& lo,
                                          uint4& hi) {
    if (wo >= 124) {
        lo = make_uint4(0u, 0u, 0u, 0u);
        hi = make_uint4(0u, 0u, 0u, 0u);
        return;
    }
    float w[20];
#pragma unroll
    for (int q = 0; q < 4; ++q) {
        w[4 * q] = f[q].x;
        w[4 * q + 1] = f[q].y;
        w[4 * q + 2] = f[q].z;
        w[4 * q + 3] = f[q].w;
    }
    if constexpr (OFF >= 2) {
        w[16] = f[4].x;
        w[17] = f[4].y;
        w[18] = f[4].z;
        w[19] = f[4].w;
    }
    lo = make_uint4(pack2(w[OFF + 0], w[OFF + 1]), pack2(w[OFF + 2], w[OFF + 3]),
                    pack2(w[OFF + 4], w[OFF + 5]), pack2(w[OFF + 6], w[OFF + 7]));
    hi = make_uint4(pack2(w[OFF + 8], w[OFF + 9]),
                    pack2(w[OFF + 10], w[OFF + 11]),
                    pack2(w[OFF + 12], w[OFF + 13]), pack2(w[OFF + 14], 0.0f));
}

// OFF = (3*wo) mod 4 where wo ≡ wid (mod 4): wid 0,1,2,3 -> OFF 0,3,2,1
#define WID_DISPATCH(...)                                   \
    switch (wid) {                                          \
        case 0: { constexpr int OFF = 0; __VA_ARGS__; } break; \
        case 1: { constexpr int OFF = 3; __VA_ARGS__; } break; \
        case 2: { constexpr int OFF = 2; __VA_ARGS__; } break; \
        default: { constexpr int OFF = 1; __VA_ARGS__; } break; \
    }

// ---------------- conv kernel: mu only, 4 groups/block, pipelined ----------
// Per group g: compute+store from LDS tile while PREFETCHING group g+1 into
// registers; raw s_barrier (no vmcnt drain) keeps mu stores in flight across
// group boundaries — stores drain while the next group computes.
__global__ __launch_bounds__(256, 3) void conv_mu_kernel(
    const float* __restrict__ mu_in,
    const unsigned short* __restrict__ w_bf,
    float* __restrict__ mu_out) {

    __shared__ __align__(16) unsigned short s_im[8 * 128 * 16];  // 32 KB

    const int tid = threadIdx.x;
    const int lane = tid & 63;
    const int wid = tid >> 6;
    const int llo = lane & 15;
    const int lhi = lane >> 4;
    const int wo_my = wid + ((lane & 31) << 2);  // this thread's staging wo
    const int rb = (lane >> 5) << 2;             // staging row base (0 or 4)

    // weights -> regs (L2-hot), once per block
    bfrag8 afr[4][3];
#pragma unroll
    for (int mt = 0; mt < 4; ++mt)
#pragma unroll
        for (int ks = 0; ks < 3; ++ks)
            afr[mt][ks] = *reinterpret_cast<const bfrag8*>(
                &w_bf[(mt * 16 + llo) * KP + ks * 32 + lhi * 8]);

    float4 f[5];
    uint4 pk[8];
    int cid = blockIdx.x;

    // ---- prologue: stage group 0 ----
    {
        const int b0 = cid / NG, h00 = (cid % NG) * 4;
        WID_DISPATCH(pair_load<OFF>(mu_in, b0, h00, rb + 0, wo_my, f));
        WID_DISPATCH(pair_pack<OFF>(f, wo_my, pk[0], pk[1]));
        WID_DISPATCH(pair_load<OFF>(mu_in, b0, h00, rb + 1, wo_my, f));
        WID_DISPATCH(pair_pack<OFF>(f, wo_my, pk[2], pk[3]));
        WID_DISPATCH(pair_load<OFF>(mu_in, b0, h00, rb + 2, wo_my, f));
        WID_DISPATCH(pair_pack<OFF>(f, wo_my, pk[4], pk[5]));
        WID_DISPATCH(pair_load<OFF>(mu_in, b0, h00, rb + 3, wo_my, f));
        WID_DISPATCH(pair_pack<OFF>(f, wo_my, pk[6], pk[7]));
#pragma unroll
        for (int j = 0; j < 4; ++j) {
            *reinterpret_cast<uint4*>((char*)s_im + im_off(rb + j, wo_my, 0)) =
                pk[2 * j];
            *reinterpret_cast<uint4*>((char*)s_im + im_off(rb + j, wo_my, 1)) =
                pk[2 * j + 1];
        }
        lds_flush();
        block_sync_nodrain();
    }

#pragma unroll
    for (int g = 0; g < GPB; ++g) {
        const int b = cid / NG;
        const int ho0 = (cid % NG) * 4;
        const int ncid = cid + NBLK;
        const bool hn = (g < GPB - 1);
        const int nb = hn ? ncid / NG : 0;
        const int nh0 = hn ? (ncid % NG) * 4 : 0;

#pragma unroll
        for (int hl = 0; hl < 4; ++hl) {
            ffrag4 acc[2][4];
#pragma unroll
            for (int nt = 0; nt < 2; ++nt)
#pragma unroll
                for (int mt = 0; mt < 4; ++mt)
                    acc[nt][mt] = (ffrag4){0.f, 0.f, 0.f, 0.f};

#pragma unroll
            for (int nt = 0; nt < 2; ++nt) {
                const int wo = (wid * 2 + nt) * 16 + llo;
#pragma unroll
                for (int ks = 0; ks < 3; ++ks) {
                    const int k0 = ks * 32 + lhi * 8;
                    const int r = k0 >> 4;  // 0..5 (5 => k>=80: zero operand)
                    bfrag8 bfr = (bfrag8){0, 0, 0, 0, 0, 0, 0, 0};
                    if (r < 5) {
                        bfr = *reinterpret_cast<const bfrag8*>(
                            (char*)s_im + im_off(hl + r, wo, (k0 & 15) >> 3));
                    }
#pragma unroll
                    for (int mt = 0; mt < 4; ++mt)
                        acc[nt][mt] = __builtin_amdgcn_mfma_f32_16x16x32_bf16(
                            afr[mt][ks], bfr, acc[nt][mt], 0, 0, 0);
                }
            }

            const size_t orow =
                (size_t)(b * HO + ho0 + hl) * (size_t)(HO * KN);
#pragma unroll
            for (int nt = 0; nt < 2; ++nt) {
                const int wo = (wid * 2 + nt) * 16 + llo;
                if (wo < HO) {
                    const size_t obase = orow + (size_t)wo * KN;
#pragma unroll
                    for (int mt = 0; mt < 4; ++mt) {
                        const int knb = mt * 16 + lhi * 4;
                        *reinterpret_cast<float4*>(&mu_out[obase + knb]) =
                            make_float4(acc[nt][mt][0], acc[nt][mt][1],
                                        acc[nt][mt][2], acc[nt][mt][3]);
                    }
                }
            }

            // interleaved prefetch of next group's tile (regs only)
            if (hn) {
                if (hl == 0) {
                    WID_DISPATCH(
                        pair_load<OFF>(mu_in, nb, nh0, rb + 0, wo_my, f));
                } else if (hl == 1) {
                    WID_DISPATCH(pair_pack<OFF>(f, wo_my, pk[0], pk[1]));
                    WID_DISPATCH(
                        pair_load<OFF>(mu_in, nb, nh0, rb + 1, wo_my, f));
                } else if (hl == 2) {
                    WID_DISPATCH(pair_pack<OFF>(f, wo_my, pk[2], pk[3]));
                    WID_DISPATCH(
                        pair_load<OFF>(mu_in, nb, nh0, rb + 2, wo_my, f));
                } else {
                    WID_DISPATCH(pair_pack<OFF>(f, wo_my, pk[4], pk[5]));
                    WID_DISPATCH(
                        pair_load<OFF>(mu_in, nb, nh0, rb + 3, wo_my, f));
                    WID_DISPATCH(pair_pack<OFF>(f, wo_my, pk[6], pk[7]));
                }
            }
        }

        if (hn) {
            block_sync_nodrain();  // all reads of s_im for group g done
#pragma unroll
            for (int j = 0; j < 4; ++j) {
                *reinterpret_cast<uint4*>((char*)s_im +
                                          im_off(rb + j, wo_my, 0)) = pk[2 * j];
                *reinterpret_cast<uint4*>((char*)s_im +
                                          im_off(rb + j, wo_my, 1)) =
                    pk[2 * j + 1];
            }
            lds_flush();
            block_sync_nodrain();  // next tile visible to all waves
        }
        cid = ncid;
    }
}

extern "C" void kernel_launch(void* const* d_in, const int* in_sizes, int n_in,
                              void* d_out, int out_size, void* d_ws,
                              size_t ws_size, hipStream_t stream) {
    const float* mu_in = (const float*)d_in[0];
    const float* w_mu = (const float*)d_in[1];
    const float* w_sigma = (const float*)d_in[2];
    float* out = (float*)d_out;

    float* mu_out = out;             // N floats
    float* sig_out = out + NOUT;     // N floats
    float* kl_out = out + 2 * NOUT;  // 1 float

    char* ws = (char*)d_ws;
    float* ssn_ws = (float*)(ws + WS_SSN_OFF);
    unsigned short* w_bf = (unsigned short*)(ws + WS_WBF_OFF);
    float* sp_ws = (float*)(ws + WS_SP_OFF);

    prep_kernel<<<1, 256, 0, stream>>>(w_mu, w_sigma, w_bf, sp_ws, kl_out);
    ssn_kernel<<<128 * NG, 256, 0, stream>>>(mu_in, ssn_ws);
    conv_mu_kernel<<<NBLK, 256, 0, stream>>>(mu_in, w_bf, mu_out);
    sigma_kernel<<<2048, 256, 0, stream>>>(ssn_ws, sp_ws, (float4*)sig_out);
}